// Round 10
// baseline (593.789 us; speedup 1.0000x reference)
//
#include <hip/hip_runtime.h>

// Round 10: T3 minimum 2-phase pipeline (stage-next || compute-current,
// double-buffered LDS, ONE __syncthreads per K-step) on all three GEMMs.
// Everything else identical to round 9 (passed, absmax 0.031).

typedef __attribute__((ext_vector_type(8))) short bf16x8;
typedef __attribute__((ext_vector_type(4))) float f32x4;
typedef unsigned short u16;
typedef unsigned int u32;

#define B_ 8
#define SQL 2048
#define SKL 2048
#define DD 1024
#define NEGC -1000000000.0f

static __device__ __forceinline__ u16 f2bf(float x) {
  u32 u = __builtin_bit_cast(u32, x);
  u32 r = u + 0x7fffu + ((u >> 16) & 1u);   // RNE
  return (u16)(r >> 16);
}
static __device__ __forceinline__ float bf2f(u16 h) {
  return __builtin_bit_cast(float, (u32)h << 16);
}
static __device__ __forceinline__ void gload16(const void* g, void* l) {
  __builtin_amdgcn_global_load_lds((const __attribute__((address_space(1))) u32*)g,
                                   (__attribute__((address_space(3))) u32*)l, 16, 0, 0);
}

// ---------------- split fp32 -> bf16 hi + bf16 lo ----------------
__global__ __launch_bounds__(256) void split_k(const float* __restrict__ in,
                                               u16* __restrict__ hi, u16* __restrict__ lo,
                                               long n) {
  long i = ((long)blockIdx.x * 256 + threadIdx.x) * 4;
  long stride = (long)gridDim.x * 256 * 4;
  for (; i < n; i += stride) {
    float4 v = *(const float4*)(in + i);
    u16 h0 = f2bf(v.x), h1 = f2bf(v.y), h2 = f2bf(v.z), h3 = f2bf(v.w);
    ushort4 H = make_ushort4(h0, h1, h2, h3);
    ushort4 L = make_ushort4(f2bf(v.x - bf2f(h0)), f2bf(v.y - bf2f(h1)),
                             f2bf(v.z - bf2f(h2)), f2bf(v.w - bf2f(h3)));
    *(ushort4*)(hi + i) = H;
    *(ushort4*)(lo + i) = L;
  }
}

// ---------------- bf16 transpose per batch: in[R][C] -> out[C][R] ----------------
__global__ __launch_bounds__(256) void transpose_k(const u16* __restrict__ in,
                                                   u16* __restrict__ out, int R, int C) {
  __shared__ u16 t[64][65];
  long bo = (long)blockIdx.z * R * C;
  int r0 = blockIdx.y * 64, c0 = blockIdx.x * 64;
  int tr = threadIdx.x / 16, tc4 = (threadIdx.x % 16) * 4;
#pragma unroll
  for (int i = 0; i < 4; ++i) {
    int r = tr + i * 16;
    ushort4 v = *(const ushort4*)(in + bo + (long)(r0 + r) * C + c0 + tc4);
    t[r][tc4 + 0] = v.x; t[r][tc4 + 1] = v.y; t[r][tc4 + 2] = v.z; t[r][tc4 + 3] = v.w;
  }
  __syncthreads();
#pragma unroll
  for (int i = 0; i < 4; ++i) {
    int c = tr + i * 16;
    ushort4 v = make_ushort4(t[tc4 + 0][c], t[tc4 + 1][c], t[tc4 + 2][c], t[tc4 + 3][c]);
    *(ushort4*)(out + bo + (long)(c0 + c) * R + r0 + tc4) = v;
  }
}

// ---------------- unified B^T-layout MFMA GEMM, 2-phase pipelined ----------------
// C[m][n] = sum_k A[m][k]*B[n][k]; 128x128 tile, 4 waves (2x2),
// mfma_f32_16x16x32_bf16, double-buffered LDS (64 KB).
// TERMS=3: BK=32, LDS row chunks = hi0-3 | lo0-3, 48 MFMA/K-step.
// TERMS=1: BK=64, LDS row chunks = hi0-7, 32 MFMA/K-step.
// OUTMODE: 0 = fp32 ; 2 = bf16 hi + lo (to C0,C1)
template <int TERMS, int OUTMODE, bool BIAS>
__global__ __launch_bounds__(256, 2) void gemm_bt(
    const u16* __restrict__ Ah, const u16* __restrict__ Al,
    const u16* __restrict__ Bh, const u16* __restrict__ Bl,
    const float* __restrict__ bias,
    void* __restrict__ C0, void* __restrict__ C1,
    int N, int K, long batchA, long batchB, long batchC) {
  constexpr int KSTEP = (TERMS > 1) ? 32 : 64;
  constexpr int RW = 64;    // u16 per LDS row (128 B)
  __shared__ u16 lA[2][128 * RW];
  __shared__ u16 lB[2][128 * RW];

  const int bz = blockIdx.z;
  const u16* pAh = Ah + (long)bz * batchA;
  const u16* pBh = Bh + (long)bz * batchB;
  const u16* pAl = (TERMS > 1) ? (Al + (long)bz * batchA) : nullptr;
  const u16* pBl = (TERMS > 1) ? (Bl + (long)bz * batchB) : nullptr;

  const int tid = threadIdx.x;
  const int l = tid & 63, w = tid >> 6;
  const int wr = w >> 1, wc = w & 1;
  const long am0 = (long)blockIdx.y * 128;
  const long bn0 = (long)blockIdx.x * 128;

  f32x4 acc[4][4];
#pragma unroll
  for (int i = 0; i < 4; ++i)
#pragma unroll
    for (int j = 0; j < 4; ++j) {
      f32x4 z = {0.f, 0.f, 0.f, 0.f};
      acc[i][j] = z;
    }

  const int srow = tid >> 3;   // 32 rows per staging issue
  const int scp = tid & 7;     // dest chunk (linear LDS position)
  const int lrow = l & 15, lch = l >> 4;

  auto STAGE = [&](int buf, int k0) {
#pragma unroll
    for (int i = 0; i < 4; ++i) {
      int row = i * 32 + srow;
      int cc = scp ^ (row & 7);   // logical chunk living at dest scp
      const u16* sA;
      const u16* sB;
      if (TERMS > 1 && cc >= 4) {
        sA = pAl + (am0 + row) * K + k0 + (cc - 4) * 8;
        sB = pBl + (bn0 + row) * K + k0 + (cc - 4) * 8;
      } else {
        sA = pAh + (am0 + row) * K + k0 + (TERMS > 1 ? (cc & 3) : cc) * 8;
        sB = pBh + (bn0 + row) * K + k0 + (TERMS > 1 ? (cc & 3) : cc) * 8;
      }
      gload16(sA, &lA[buf][row * RW + scp * 8]);
      gload16(sB, &lB[buf][row * RW + scp * 8]);
    }
  };

  auto COMPUTE = [&](int buf) {
    if (TERMS > 1) {
      bf16x8 ah[4], bh[4], al_[4], bl_[4];
#pragma unroll
      for (int f = 0; f < 4; ++f) {
        int ra = wr * 64 + f * 16 + lrow;
        int rb = wc * 64 + f * 16 + lrow;
        ah[f] = *(const bf16x8*)&lA[buf][ra * RW + (lch ^ (ra & 7)) * 8];
        bh[f] = *(const bf16x8*)&lB[buf][rb * RW + (lch ^ (rb & 7)) * 8];
        al_[f] = *(const bf16x8*)&lA[buf][ra * RW + ((4 + lch) ^ (ra & 7)) * 8];
        bl_[f] = *(const bf16x8*)&lB[buf][rb * RW + ((4 + lch) ^ (rb & 7)) * 8];
      }
#pragma unroll
      for (int mf = 0; mf < 4; ++mf)
#pragma unroll
        for (int nf = 0; nf < 4; ++nf) {
          acc[mf][nf] = __builtin_amdgcn_mfma_f32_16x16x32_bf16(ah[mf], bh[nf], acc[mf][nf], 0, 0, 0);
          acc[mf][nf] = __builtin_amdgcn_mfma_f32_16x16x32_bf16(ah[mf], bl_[nf], acc[mf][nf], 0, 0, 0);
          acc[mf][nf] = __builtin_amdgcn_mfma_f32_16x16x32_bf16(al_[mf], bh[nf], acc[mf][nf], 0, 0, 0);
        }
    } else {
#pragma unroll
      for (int kk = 0; kk < 2; ++kk) {
        bf16x8 ah[4], bh[4];
#pragma unroll
        for (int f = 0; f < 4; ++f) {
          int ra = wr * 64 + f * 16 + lrow;
          int rb = wc * 64 + f * 16 + lrow;
          int c = kk * 4 + lch;
          ah[f] = *(const bf16x8*)&lA[buf][ra * RW + (c ^ (ra & 7)) * 8];
          bh[f] = *(const bf16x8*)&lB[buf][rb * RW + (c ^ (rb & 7)) * 8];
        }
#pragma unroll
        for (int mf = 0; mf < 4; ++mf)
#pragma unroll
          for (int nf = 0; nf < 4; ++nf)
            acc[mf][nf] = __builtin_amdgcn_mfma_f32_16x16x32_bf16(ah[mf], bh[nf], acc[mf][nf], 0, 0, 0);
      }
    }
  };

  // ---- 2-phase pipeline: stage(t+1) overlaps compute(t); one barrier/iter ----
  STAGE(0, 0);
  __syncthreads();           // prologue drain + sync (once per block)
  int cur = 0;
  for (int k0 = KSTEP; k0 < K; k0 += KSTEP) {
    STAGE(cur ^ 1, k0);      // loads fly during COMPUTE below
    COMPUTE(cur);
    __syncthreads();         // implicit vmcnt(0) drain (cheap: loads had whole
    cur ^= 1;                //  compute to land) + cross-wave visibility
  }
  COMPUTE(cur);              // last K-step, no prefetch

  // epilogue: C/D layout col = lane&15, row = (lane>>4)*4 + reg
#pragma unroll
  for (int mf = 0; mf < 4; ++mf)
#pragma unroll
    for (int nf = 0; nf < 4; ++nf)
#pragma unroll
      for (int r = 0; r < 4; ++r) {
        long row = am0 + wr * 64 + mf * 16 + (l >> 4) * 4 + r;
        long col = bn0 + wc * 64 + nf * 16 + (l & 15);
        float v = acc[mf][nf][r];
        if (BIAS) v += bias[col];
        long idx = (long)bz * batchC + row * N + col;
        if (OUTMODE == 0) {
          ((float*)C0)[idx] = v;
        } else {
          u16 h = f2bf(v);
          ((u16*)C0)[idx] = h;
          ((u16*)C1)[idx] = f2bf(v - bf2f(h));
        }
      }
}

// ---------------- mask + row softmax: S fp32 -> P bf16 ----------------
__global__ __launch_bounds__(256) void softmax_k(const float* __restrict__ S,
                                                 const int* __restrict__ M,
                                                 u16* __restrict__ P) {
  long row = blockIdx.x;
  const float* s = S + row * SKL;
  const int* m = M + row * SKL;
  u16* p = P + row * SKL;
  int t = threadIdx.x;
  float x[8];
#pragma unroll
  for (int j = 0; j < 2; ++j) {
    float4 v = *(const float4*)(s + t * 8 + j * 4);
    int4 q = *(const int4*)(m + t * 8 + j * 4);
    x[j * 4 + 0] = q.x ? v.x : v.x + NEGC;
    x[j * 4 + 1] = q.y ? v.y : v.y + NEGC;
    x[j * 4 + 2] = q.z ? v.z : v.z + NEGC;
    x[j * 4 + 3] = q.w ? v.w : v.w + NEGC;
  }
  float mx = x[0];
#pragma unroll
  for (int j = 1; j < 8; ++j) mx = fmaxf(mx, x[j]);
#pragma unroll
  for (int o = 32; o >= 1; o >>= 1) mx = fmaxf(mx, __shfl_xor(mx, o, 64));
  __shared__ float red[8];
  if ((t & 63) == 0) red[t >> 6] = mx;
  __syncthreads();
  mx = fmaxf(fmaxf(red[0], red[1]), fmaxf(red[2], red[3]));
  float e[8], sum = 0.f;
#pragma unroll
  for (int j = 0; j < 8; ++j) { e[j] = __expf(x[j] - mx); sum += e[j]; }
#pragma unroll
  for (int o = 32; o >= 1; o >>= 1) sum += __shfl_xor(sum, o, 64);
  if ((t & 63) == 0) red[4 + (t >> 6)] = sum;
  __syncthreads();
  float inv = 1.f / (red[4] + red[5] + red[6] + red[7]);
  ushort4 o0 = make_ushort4(f2bf(e[0] * inv), f2bf(e[1] * inv), f2bf(e[2] * inv), f2bf(e[3] * inv));
  ushort4 o1 = make_ushort4(f2bf(e[4] * inv), f2bf(e[5] * inv), f2bf(e[6] * inv), f2bf(e[7] * inv));
  *(ushort4*)(p + t * 8) = o0;
  *(ushort4*)(p + t * 8 + 4) = o1;
}

extern "C" void kernel_launch(void* const* d_in, const int* in_sizes, int n_in,
                              void* d_out, int out_size, void* d_ws, size_t ws_size,
                              hipStream_t stream) {
  const float* query = (const float*)d_in[0];
  const float* mem = (const float*)d_in[1];
  const int* mask = (const int*)d_in[2];
  const float* Wm = (const float*)d_in[3];
  const float* bias = (const float*)d_in[4];
  float* out = (float*)d_out;   // fp32 output

  const long nQ = (long)B_ * SQL * DD;   // 16.7M
  const long nW = (long)DD * DD;
  const long nS = (long)B_ * SQL * SKL;

  char* ws = (char*)d_ws;
  u16* qh = (u16*)ws; ws += nQ * 2;
  u16* ql = (u16*)ws; ws += nQ * 2;
  u16* mh = (u16*)ws; ws += nQ * 2;
  u16* ml = (u16*)ws; ws += nQ * 2;
  u16* mt = (u16*)ws; ws += nQ * 2;
  u16* ph = (u16*)ws; ws += nQ * 2;
  u16* pl = (u16*)ws; ws += nQ * 2;
  u16* wh = (u16*)ws; ws += nW * 2;
  u16* wl = (u16*)ws; ws += nW * 2;
  float* S = (float*)ws; ws += nS * 4;
  u16* P = qh;   // qh+ql (67MB adjacent) dead after projection

  split_k<<<2048, 256, 0, stream>>>(query, qh, ql, nQ);
  split_k<<<2048, 256, 0, stream>>>(mem, mh, ml, nQ);
  split_k<<<512, 256, 0, stream>>>(Wm, wh, wl, nW);
  transpose_k<<<dim3(DD / 64, SKL / 64, B_), 256, 0, stream>>>(mh, mt, SKL, DD);

  // projection: M=16384, N=D, K=D ; writes q as hi/lo
  gemm_bt<3, 2, true><<<dim3(DD / 128, (B_ * SQL) / 128, 1), 256, 0, stream>>>(
      qh, ql, wh, wl, bias, ph, pl, DD, DD, 0, 0, 0);
  // logits: per batch M=Sq, N=Sk, K=D ; fp32 S
  gemm_bt<3, 0, false><<<dim3(SKL / 128, SQL / 128, B_), 256, 0, stream>>>(
      ph, pl, mh, ml, nullptr, S, nullptr, SKL, DD,
      (long)SQL * DD, (long)SKL * DD, (long)SQL * SKL);
  // mask + softmax -> P bf16
  softmax_k<<<B_ * SQL, 256, 0, stream>>>(S, mask, P);
  // PV: per batch M=Sq, N=D, K=Sk ; B = mem_hi transposed [D][Sk] ; fp32 out
  gemm_bt<1, 0, false><<<dim3(DD / 128, SQL / 128, B_), 256, 0, stream>>>(
      P, nullptr, mt, nullptr, nullptr, out, nullptr, DD, SKL,
      (long)SQL * SKL, (long)DD * SKL, (long)SQL * DD);
}

// Round 11
// 560.938 us; speedup vs baseline: 1.0586x; 1.0586x over previous
//
#include <hip/hip_runtime.h>

// Round 11: revert to R9 single-buffer GEMM (R10 dbuf regressed via occupancy:
// 32->64KB LDS, occ 30->22%, MfmaUtil 44->36%). Add two fusions:
//  (a) mask folded into QK epilogue (S written pre-masked; softmax reads S only)
//  (b) mem split + transpose fused into one kernel (mh, ml, mt in one pass)

typedef __attribute__((ext_vector_type(8))) short bf16x8;
typedef __attribute__((ext_vector_type(4))) float f32x4;
typedef unsigned short u16;
typedef unsigned int u32;

#define B_ 8
#define SQL 2048
#define SKL 2048
#define DD 1024
#define NEGC -1000000000.0f

static __device__ __forceinline__ u16 f2bf(float x) {
  u32 u = __builtin_bit_cast(u32, x);
  u32 r = u + 0x7fffu + ((u >> 16) & 1u);   // RNE
  return (u16)(r >> 16);
}
static __device__ __forceinline__ float bf2f(u16 h) {
  return __builtin_bit_cast(float, (u32)h << 16);
}
static __device__ __forceinline__ void gload16(const void* g, void* l) {
  __builtin_amdgcn_global_load_lds((const __attribute__((address_space(1))) u32*)g,
                                   (__attribute__((address_space(3))) u32*)l, 16, 0, 0);
}

// ---------------- split fp32 -> bf16 hi + bf16 lo ----------------
__global__ __launch_bounds__(256) void split_k(const float* __restrict__ in,
                                               u16* __restrict__ hi, u16* __restrict__ lo,
                                               long n) {
  long i = ((long)blockIdx.x * 256 + threadIdx.x) * 4;
  long stride = (long)gridDim.x * 256 * 4;
  for (; i < n; i += stride) {
    float4 v = *(const float4*)(in + i);
    u16 h0 = f2bf(v.x), h1 = f2bf(v.y), h2 = f2bf(v.z), h3 = f2bf(v.w);
    ushort4 H = make_ushort4(h0, h1, h2, h3);
    ushort4 L = make_ushort4(f2bf(v.x - bf2f(h0)), f2bf(v.y - bf2f(h1)),
                             f2bf(v.z - bf2f(h2)), f2bf(v.w - bf2f(h3)));
    *(ushort4*)(hi + i) = H;
    *(ushort4*)(lo + i) = L;
  }
}

// ---------------- fused mem split + transpose: fp32 [Sk][D] -> mh, ml, mt[D][Sk] ----------------
__global__ __launch_bounds__(256) void split_mem_k(const float* __restrict__ in,
                                                   u16* __restrict__ hi, u16* __restrict__ lo,
                                                   u16* __restrict__ trn) {
  __shared__ u16 t[64][65];
  long bo = (long)blockIdx.z * SKL * DD;
  int r0 = blockIdx.y * 64, c0 = blockIdx.x * 64;
  int tr = threadIdx.x / 16, tc4 = (threadIdx.x % 16) * 4;
#pragma unroll
  for (int i = 0; i < 4; ++i) {
    int r = tr + i * 16;
    long idx = bo + (long)(r0 + r) * DD + c0 + tc4;
    float4 v = *(const float4*)(in + idx);
    u16 h0 = f2bf(v.x), h1 = f2bf(v.y), h2 = f2bf(v.z), h3 = f2bf(v.w);
    *(ushort4*)(hi + idx) = make_ushort4(h0, h1, h2, h3);
    *(ushort4*)(lo + idx) = make_ushort4(f2bf(v.x - bf2f(h0)), f2bf(v.y - bf2f(h1)),
                                         f2bf(v.z - bf2f(h2)), f2bf(v.w - bf2f(h3)));
    t[r][tc4 + 0] = h0; t[r][tc4 + 1] = h1; t[r][tc4 + 2] = h2; t[r][tc4 + 3] = h3;
  }
  __syncthreads();
#pragma unroll
  for (int i = 0; i < 4; ++i) {
    int c = tr + i * 16;   // output row = original column c0+c
    ushort4 v = make_ushort4(t[tc4 + 0][c], t[tc4 + 1][c], t[tc4 + 2][c], t[tc4 + 3][c]);
    *(ushort4*)(trn + bo + (long)(c0 + c) * SKL + r0 + tc4) = v;
  }
}

// ---------------- unified B^T-layout MFMA GEMM (R9 single-buffer structure) ----------------
// C[m][n] = sum_k A[m][k]*B[n][k]; 128x128 tile, 4 waves (2x2),
// mfma_f32_16x16x32_bf16. LDS row = 8 x 16B chunks, XOR-swizzled via
// pre-swizzled global source (global_load_lds dest stays linear).
// TERMS=3: BK=32, chunks = hi0-3 | lo0-3. TERMS=1: BK=64, chunks = hi0-7.
// OUTMODE: 0 = fp32 ; 2 = bf16 hi + lo. MASKED: add (1-mask)*NEG in epilogue.
template <int TERMS, int OUTMODE, bool BIAS, bool MASKED>
__global__ __launch_bounds__(256, 2) void gemm_bt(
    const u16* __restrict__ Ah, const u16* __restrict__ Al,
    const u16* __restrict__ Bh, const u16* __restrict__ Bl,
    const float* __restrict__ bias, const int* __restrict__ Msk,
    void* __restrict__ C0, void* __restrict__ C1,
    int N, int K, long batchA, long batchB, long batchC) {
  constexpr int KSTEP = (TERMS > 1) ? 32 : 64;
  constexpr int RW = 64;    // u16 per LDS row (128 B)
  __shared__ u16 lA[128 * RW];
  __shared__ u16 lB[128 * RW];

  const int bz = blockIdx.z;
  const u16* pAh = Ah + (long)bz * batchA;
  const u16* pBh = Bh + (long)bz * batchB;
  const u16* pAl = (TERMS > 1) ? (Al + (long)bz * batchA) : nullptr;
  const u16* pBl = (TERMS > 1) ? (Bl + (long)bz * batchB) : nullptr;

  const int tid = threadIdx.x;
  const int l = tid & 63, w = tid >> 6;
  const int wr = w >> 1, wc = w & 1;
  const long am0 = (long)blockIdx.y * 128;
  const long bn0 = (long)blockIdx.x * 128;

  f32x4 acc[4][4];
#pragma unroll
  for (int i = 0; i < 4; ++i)
#pragma unroll
    for (int j = 0; j < 4; ++j) {
      f32x4 z = {0.f, 0.f, 0.f, 0.f};
      acc[i][j] = z;
    }

  const int srow = tid >> 3;   // 32 rows per staging issue
  const int scp = tid & 7;     // dest chunk (linear LDS position)
  const int lrow = l & 15, lch = l >> 4;

  for (int k0 = 0; k0 < K; k0 += KSTEP) {
    __syncthreads();
#pragma unroll
    for (int i = 0; i < 4; ++i) {
      int row = i * 32 + srow;
      int cc = scp ^ (row & 7);   // logical chunk living at dest scp
      const u16* sA;
      const u16* sB;
      if (TERMS > 1 && cc >= 4) {
        sA = pAl + (am0 + row) * K + k0 + (cc - 4) * 8;
        sB = pBl + (bn0 + row) * K + k0 + (cc - 4) * 8;
      } else {
        sA = pAh + (am0 + row) * K + k0 + (TERMS > 1 ? (cc & 3) : cc) * 8;
        sB = pBh + (bn0 + row) * K + k0 + (TERMS > 1 ? (cc & 3) : cc) * 8;
      }
      gload16(sA, &lA[row * RW + scp * 8]);
      gload16(sB, &lB[row * RW + scp * 8]);
    }
    __syncthreads();

    if (TERMS > 1) {
      bf16x8 ah[4], bh[4], al_[4], bl_[4];
#pragma unroll
      for (int f = 0; f < 4; ++f) {
        int ra = wr * 64 + f * 16 + lrow;
        int rb = wc * 64 + f * 16 + lrow;
        ah[f] = *(const bf16x8*)&lA[ra * RW + (lch ^ (ra & 7)) * 8];
        bh[f] = *(const bf16x8*)&lB[rb * RW + (lch ^ (rb & 7)) * 8];
        al_[f] = *(const bf16x8*)&lA[ra * RW + ((4 + lch) ^ (ra & 7)) * 8];
        bl_[f] = *(const bf16x8*)&lB[rb * RW + ((4 + lch) ^ (rb & 7)) * 8];
      }
#pragma unroll
      for (int mf = 0; mf < 4; ++mf)
#pragma unroll
        for (int nf = 0; nf < 4; ++nf) {
          acc[mf][nf] = __builtin_amdgcn_mfma_f32_16x16x32_bf16(ah[mf], bh[nf], acc[mf][nf], 0, 0, 0);
          acc[mf][nf] = __builtin_amdgcn_mfma_f32_16x16x32_bf16(ah[mf], bl_[nf], acc[mf][nf], 0, 0, 0);
          acc[mf][nf] = __builtin_amdgcn_mfma_f32_16x16x32_bf16(al_[mf], bh[nf], acc[mf][nf], 0, 0, 0);
        }
    } else {
#pragma unroll
      for (int kk = 0; kk < 2; ++kk) {
        bf16x8 ah[4], bh[4];
#pragma unroll
        for (int f = 0; f < 4; ++f) {
          int ra = wr * 64 + f * 16 + lrow;
          int rb = wc * 64 + f * 16 + lrow;
          int c = kk * 4 + lch;
          ah[f] = *(const bf16x8*)&lA[ra * RW + (c ^ (ra & 7)) * 8];
          bh[f] = *(const bf16x8*)&lB[rb * RW + (c ^ (rb & 7)) * 8];
        }
#pragma unroll
        for (int mf = 0; mf < 4; ++mf)
#pragma unroll
          for (int nf = 0; nf < 4; ++nf)
            acc[mf][nf] = __builtin_amdgcn_mfma_f32_16x16x32_bf16(ah[mf], bh[nf], acc[mf][nf], 0, 0, 0);
      }
    }
  }

  // epilogue: C/D layout col = lane&15, row = (lane>>4)*4 + reg
  const int* pM = MASKED ? (Msk + (long)bz * batchC) : nullptr;
#pragma unroll
  for (int mf = 0; mf < 4; ++mf)
#pragma unroll
    for (int nf = 0; nf < 4; ++nf)
#pragma unroll
      for (int r = 0; r < 4; ++r) {
        long row = am0 + wr * 64 + mf * 16 + (l >> 4) * 4 + r;
        long col = bn0 + wc * 64 + nf * 16 + (l & 15);
        float v = acc[mf][nf][r];
        if (BIAS) v += bias[col];
        long off = row * N + col;
        if (MASKED) v += pM[off] ? 0.f : NEGC;
        long idx = (long)bz * batchC + off;
        if (OUTMODE == 0) {
          ((float*)C0)[idx] = v;
        } else {
          u16 h = f2bf(v);
          ((u16*)C0)[idx] = h;
          ((u16*)C1)[idx] = f2bf(v - bf2f(h));
        }
      }
}

// ---------------- row softmax (S already masked): fp32 -> P bf16 ----------------
__global__ __launch_bounds__(256) void softmax_k(const float* __restrict__ S,
                                                 u16* __restrict__ P) {
  long row = blockIdx.x;
  const float* s = S + row * SKL;
  u16* p = P + row * SKL;
  int t = threadIdx.x;
  float x[8];
#pragma unroll
  for (int j = 0; j < 2; ++j) {
    float4 v = *(const float4*)(s + t * 8 + j * 4);
    x[j * 4 + 0] = v.x; x[j * 4 + 1] = v.y; x[j * 4 + 2] = v.z; x[j * 4 + 3] = v.w;
  }
  float mx = x[0];
#pragma unroll
  for (int j = 1; j < 8; ++j) mx = fmaxf(mx, x[j]);
#pragma unroll
  for (int o = 32; o >= 1; o >>= 1) mx = fmaxf(mx, __shfl_xor(mx, o, 64));
  __shared__ float red[8];
  if ((t & 63) == 0) red[t >> 6] = mx;
  __syncthreads();
  mx = fmaxf(fmaxf(red[0], red[1]), fmaxf(red[2], red[3]));
  float e[8], sum = 0.f;
#pragma unroll
  for (int j = 0; j < 8; ++j) { e[j] = __expf(x[j] - mx); sum += e[j]; }
#pragma unroll
  for (int o = 32; o >= 1; o >>= 1) sum += __shfl_xor(sum, o, 64);
  if ((t & 63) == 0) red[4 + (t >> 6)] = sum;
  __syncthreads();
  float inv = 1.f / (red[4] + red[5] + red[6] + red[7]);
  ushort4 o0 = make_ushort4(f2bf(e[0] * inv), f2bf(e[1] * inv), f2bf(e[2] * inv), f2bf(e[3] * inv));
  ushort4 o1 = make_ushort4(f2bf(e[4] * inv), f2bf(e[5] * inv), f2bf(e[6] * inv), f2bf(e[7] * inv));
  *(ushort4*)(p + t * 8) = o0;
  *(ushort4*)(p + t * 8 + 4) = o1;
}

extern "C" void kernel_launch(void* const* d_in, const int* in_sizes, int n_in,
                              void* d_out, int out_size, void* d_ws, size_t ws_size,
                              hipStream_t stream) {
  const float* query = (const float*)d_in[0];
  const float* mem = (const float*)d_in[1];
  const int* mask = (const int*)d_in[2];
  const float* Wm = (const float*)d_in[3];
  const float* bias = (const float*)d_in[4];
  float* out = (float*)d_out;   // fp32 output

  const long nQ = (long)B_ * SQL * DD;   // 16.7M
  const long nW = (long)DD * DD;
  const long nS = (long)B_ * SQL * SKL;

  char* ws = (char*)d_ws;
  u16* qh = (u16*)ws; ws += nQ * 2;
  u16* ql = (u16*)ws; ws += nQ * 2;
  u16* mh = (u16*)ws; ws += nQ * 2;
  u16* ml = (u16*)ws; ws += nQ * 2;
  u16* mt = (u16*)ws; ws += nQ * 2;
  u16* ph = (u16*)ws; ws += nQ * 2;
  u16* pl = (u16*)ws; ws += nQ * 2;
  u16* wh = (u16*)ws; ws += nW * 2;
  u16* wl = (u16*)ws; ws += nW * 2;
  float* S = (float*)ws; ws += nS * 4;
  u16* P = qh;   // qh+ql (67MB adjacent) dead after projection

  split_k<<<2048, 256, 0, stream>>>(query, qh, ql, nQ);
  split_k<<<512, 256, 0, stream>>>(Wm, wh, wl, nW);
  // fused: mem -> mh, ml, mt (transpose included)
  split_mem_k<<<dim3(DD / 64, SKL / 64, B_), 256, 0, stream>>>(mem, mh, ml, mt);

  // projection: M=16384, N=D, K=D ; writes q as hi/lo
  gemm_bt<3, 2, true, false><<<dim3(DD / 128, (B_ * SQL) / 128, 1), 256, 0, stream>>>(
      qh, ql, wh, wl, bias, nullptr, ph, pl, DD, DD, 0, 0, 0);
  // logits: per batch M=Sq, N=Sk, K=D ; fp32 S, mask fused in epilogue
  gemm_bt<3, 0, false, true><<<dim3(SKL / 128, SQL / 128, B_), 256, 0, stream>>>(
      ph, pl, mh, ml, nullptr, mask, S, nullptr, SKL, DD,
      (long)SQL * DD, (long)SKL * DD, (long)SQL * SKL);
  // softmax on pre-masked S -> P bf16
  softmax_k<<<B_ * SQL, 256, 0, stream>>>(S, P);
  // PV: per batch M=Sq, N=D, K=Sk ; B = mem_hi transposed [D][Sk] ; fp32 out
  gemm_bt<1, 0, false, false><<<dim3(DD / 128, SQL / 128, B_), 256, 0, stream>>>(
      P, nullptr, mt, nullptr, nullptr, nullptr, out, nullptr, DD, SKL,
      (long)SQL * SKL, (long)DD * SKL, (long)SQL * DD);
}